// Round 1
// baseline (708.758 us; speedup 1.0000x reference)
//
#include <hip/hip_runtime.h>
#include <math.h>

namespace {
constexpr int   D       = 8;
constexpr int   H       = 4096;
constexpr int   SB      = 2048 * 2;            // S*B
constexpr long  DSTRIDE = (long)SB * H;        // depth stride in elements
constexpr float EPS     = 1e-6f;
constexpr int   BLOCK   = 512;                 // 8 waves
}

__global__ __launch_bounds__(BLOCK, 2) void fullattnres_kernel(
    const float* __restrict__ values,
    const float* __restrict__ query,
    const float* __restrict__ weight,
    float* __restrict__ out)
{
    const int sb   = blockIdx.x;
    const int t    = threadIdx.x;
    const int lane = t & 63;
    const int wav  = t >> 6;

    const long base = (long)sb * H;
    const int  h0   = t * 4;           // covers [0, 2048)
    const int  h1   = 2048 + t * 4;    // covers [2048, 4096)

    // qw[h] = query[h] * weight[h] (reused across all 8 depths)
    const float4 q0 = *reinterpret_cast<const float4*>(query  + h0);
    const float4 q1 = *reinterpret_cast<const float4*>(query  + h1);
    const float4 w0 = *reinterpret_cast<const float4*>(weight + h0);
    const float4 w1 = *reinterpret_cast<const float4*>(weight + h1);
    const float4 qw0 = make_float4(q0.x*w0.x, q0.y*w0.y, q0.z*w0.z, q0.w*w0.w);
    const float4 qw1 = make_float4(q1.x*w1.x, q1.y*w1.y, q1.z*w1.z, q1.w*w1.w);

    // Load all depths once into registers (values read exactly once from HBM)
    float4 v0[D], v1[D];
    #pragma unroll
    for (int d = 0; d < D; ++d) {
        const float* p = values + (long)d * DSTRIDE + base;
        v0[d] = *reinterpret_cast<const float4*>(p + h0);
        v1[d] = *reinterpret_cast<const float4*>(p + h1);
    }

    // Per-thread partial reductions: sum(v*v) and sum(qw*v) per depth
    float ss[D], dt[D];
    #pragma unroll
    for (int d = 0; d < D; ++d) {
        const float4 a = v0[d], b = v1[d];
        ss[d] = a.x*a.x + a.y*a.y + a.z*a.z + a.w*a.w
              + b.x*b.x + b.y*b.y + b.z*b.z + b.w*b.w;
        dt[d] = qw0.x*a.x + qw0.y*a.y + qw0.z*a.z + qw0.w*a.w
              + qw1.x*b.x + qw1.y*b.y + qw1.z*b.z + qw1.w*b.w;
    }

    // Wave-level butterfly reduction (64 lanes)
    #pragma unroll
    for (int d = 0; d < D; ++d) {
        #pragma unroll
        for (int off = 32; off > 0; off >>= 1) {
            ss[d] += __shfl_down(ss[d], off);
            dt[d] += __shfl_down(dt[d], off);
        }
    }

    __shared__ float red_ss[BLOCK / 64][D];
    __shared__ float red_dt[BLOCK / 64][D];
    __shared__ float logits[D];
    __shared__ float wts[D];

    if (lane == 0) {
        #pragma unroll
        for (int d = 0; d < D; ++d) {
            red_ss[wav][d] = ss[d];
            red_dt[wav][d] = dt[d];
        }
    }
    __syncthreads();

    // 8 threads: combine wave partials -> logit per depth
    if (t < D) {
        float s = 0.f, p = 0.f;
        #pragma unroll
        for (int w = 0; w < BLOCK / 64; ++w) {
            s += red_ss[w][t];
            p += red_dt[w][t];
        }
        logits[t] = p * rsqrtf(s * (1.0f / H) + EPS);
    }
    __syncthreads();

    // 8 threads: softmax over depth (each computes its own weight)
    if (t < D) {
        float m = logits[0];
        #pragma unroll
        for (int d = 1; d < D; ++d) m = fmaxf(m, logits[d]);
        float sum = 0.f;
        #pragma unroll
        for (int d = 0; d < D; ++d) sum += expf(logits[d] - m);
        wts[t] = expf(logits[t] - m) / sum;
    }
    __syncthreads();

    float wl[D];
    #pragma unroll
    for (int d = 0; d < D; ++d) wl[d] = wts[d];

    // Weighted recombine from registers (no second HBM read of values)
    float4 o0 = make_float4(0.f, 0.f, 0.f, 0.f);
    float4 o1 = make_float4(0.f, 0.f, 0.f, 0.f);
    #pragma unroll
    for (int d = 0; d < D; ++d) {
        o0.x += wl[d] * v0[d].x;  o0.y += wl[d] * v0[d].y;
        o0.z += wl[d] * v0[d].z;  o0.w += wl[d] * v0[d].w;
        o1.x += wl[d] * v1[d].x;  o1.y += wl[d] * v1[d].y;
        o1.z += wl[d] * v1[d].z;  o1.w += wl[d] * v1[d].w;
    }
    *reinterpret_cast<float4*>(out + base + h0) = o0;
    *reinterpret_cast<float4*>(out + base + h1) = o1;
}

extern "C" void kernel_launch(void* const* d_in, const int* in_sizes, int n_in,
                              void* d_out, int out_size, void* d_ws, size_t ws_size,
                              hipStream_t stream) {
    const float* values = (const float*)d_in[0];
    const float* query  = (const float*)d_in[1];
    const float* weight = (const float*)d_in[2];
    float* out = (float*)d_out;

    fullattnres_kernel<<<SB, BLOCK, 0, stream>>>(values, query, weight, out);
}

// Round 2
// 707.475 us; speedup vs baseline: 1.0018x; 1.0018x over previous
//
#include <hip/hip_runtime.h>
#include <math.h>

namespace {
constexpr int   D       = 8;
constexpr int   H       = 4096;
constexpr int   SB      = 2048 * 2;            // S*B
constexpr long  DSTRIDE = (long)SB * H;        // depth stride in elements
constexpr float EPS     = 1e-6f;
constexpr int   BLOCK   = 512;                 // 8 waves
constexpr int   NWAVE   = BLOCK / 64;
}

// __launch_bounds__(512,4): 4 waves/SIMD -> VGPR cap 128 -> 2 blocks/CU.
// One block's load burst overlaps the other's reduce/softmax/recombine bubble.
__global__ __launch_bounds__(BLOCK, 4) void fullattnres_kernel(
    const float* __restrict__ values,
    const float* __restrict__ query,
    const float* __restrict__ weight,
    float* __restrict__ out)
{
    const int sb   = blockIdx.x;
    const int t    = threadIdx.x;
    const int lane = t & 63;
    const int wav  = t >> 6;

    const long base = (long)sb * H;
    const int  h0   = t * 4;           // [0, 2048)
    const int  h1   = 2048 + t * 4;    // [2048, 4096)

    // qw[h] = query[h] * weight[h]; dead after the dot-product phase
    const float4 q0 = *reinterpret_cast<const float4*>(query  + h0);
    const float4 q1 = *reinterpret_cast<const float4*>(query  + h1);
    const float4 w0 = *reinterpret_cast<const float4*>(weight + h0);
    const float4 w1 = *reinterpret_cast<const float4*>(weight + h1);
    const float4 qw0 = make_float4(q0.x*w0.x, q0.y*w0.y, q0.z*w0.z, q0.w*w0.w);
    const float4 qw1 = make_float4(q1.x*w1.x, q1.y*w1.y, q1.z*w1.z, q1.w*w1.w);

    // Load all depths once (values touch HBM exactly once); fold partials
    // per depth so only v0/v1 (64 VGPRs) stay live across the barrier.
    float4 v0[D], v1[D];
    float ss[D], dt[D];
    #pragma unroll
    for (int d = 0; d < D; ++d) {
        const float* p = values + (long)d * DSTRIDE + base;
        v0[d] = *reinterpret_cast<const float4*>(p + h0);
        v1[d] = *reinterpret_cast<const float4*>(p + h1);
        const float4 a = v0[d], b = v1[d];
        ss[d] = a.x*a.x + a.y*a.y + a.z*a.z + a.w*a.w
              + b.x*b.x + b.y*b.y + b.z*b.z + b.w*b.w;
        dt[d] = qw0.x*a.x + qw0.y*a.y + qw0.z*a.z + qw0.w*a.w
              + qw1.x*b.x + qw1.y*b.y + qw1.z*b.z + qw1.w*b.w;
    }

    // 64-lane butterfly reduction per depth
    #pragma unroll
    for (int d = 0; d < D; ++d) {
        #pragma unroll
        for (int off = 32; off > 0; off >>= 1) {
            ss[d] += __shfl_down(ss[d], off);
            dt[d] += __shfl_down(dt[d], off);
        }
    }

    __shared__ float red_ss[NWAVE][D];
    __shared__ float red_dt[NWAVE][D];

    if (lane == 0) {
        #pragma unroll
        for (int d = 0; d < D; ++d) {
            red_ss[wav][d] = ss[d];
            red_dt[wav][d] = dt[d];
        }
    }
    __syncthreads();   // the ONLY barrier

    // Every thread redundantly combines the 8x8 partial table (LDS
    // broadcast reads) and computes logits + softmax locally -> no
    // second/third barrier, no weight broadcast round-trip.
    float lg[D];
    #pragma unroll
    for (int d = 0; d < D; ++d) {
        float s = 0.f, p = 0.f;
        #pragma unroll
        for (int w = 0; w < NWAVE; ++w) {
            s += red_ss[w][d];
            p += red_dt[w][d];
        }
        lg[d] = p * rsqrtf(s * (1.0f / H) + EPS);
    }
    float m = lg[0];
    #pragma unroll
    for (int d = 1; d < D; ++d) m = fmaxf(m, lg[d]);
    float sum = 0.f;
    float wl[D];
    #pragma unroll
    for (int d = 0; d < D; ++d) { wl[d] = expf(lg[d] - m); sum += wl[d]; }
    const float inv = 1.0f / sum;
    #pragma unroll
    for (int d = 0; d < D; ++d) wl[d] *= inv;

    // Weighted recombine from registers (no second HBM read of values)
    float4 o0 = make_float4(0.f, 0.f, 0.f, 0.f);
    float4 o1 = make_float4(0.f, 0.f, 0.f, 0.f);
    #pragma unroll
    for (int d = 0; d < D; ++d) {
        o0.x += wl[d] * v0[d].x;  o0.y += wl[d] * v0[d].y;
        o0.z += wl[d] * v0[d].z;  o0.w += wl[d] * v0[d].w;
        o1.x += wl[d] * v1[d].x;  o1.y += wl[d] * v1[d].y;
        o1.z += wl[d] * v1[d].z;  o1.w += wl[d] * v1[d].w;
    }
    *reinterpret_cast<float4*>(out + base + h0) = o0;
    *reinterpret_cast<float4*>(out + base + h1) = o1;
}

extern "C" void kernel_launch(void* const* d_in, const int* in_sizes, int n_in,
                              void* d_out, int out_size, void* d_ws, size_t ws_size,
                              hipStream_t stream) {
    const float* values = (const float*)d_in[0];
    const float* query  = (const float*)d_in[1];
    const float* weight = (const float*)d_in[2];
    float* out = (float*)d_out;

    fullattnres_kernel<<<SB, BLOCK, 0, stream>>>(values, query, weight, out);
}